// Round 3
// baseline (1142.306 us; speedup 1.0000x reference)
//
#include <hip/hip_runtime.h>
#include <hip/hip_bf16.h>
#include <math.h>

#define EMB 128
#define OUT 256
#define RAD 6
#define NDL 3
#define NTGT 12
#define MT 32          // nodes per chain block
#define S 264          // LDS activation stride (bf16 elems)

typedef __attribute__((ext_vector_type(8))) short short8;
typedef __attribute__((ext_vector_type(4))) float floatx4;

__device__ inline short f2bf(float x) {
    __hip_bfloat16 h = __float2bfloat16(x);
    return *reinterpret_cast<short*>(&h);
}

__device__ inline unsigned pack2bf(float x, float y) {
    unsigned a = (unsigned short)f2bf(x);
    unsigned b = (unsigned short)f2bf(y);
    return a | (b << 16);
}

// ---------------- weight prep: bf16 + transpose ----------------

__global__ void prep_kernel(const float* __restrict__ w_up, const float* __restrict__ w_dense,
                            const float* __restrict__ w_final,
                            short* __restrict__ w_upT, short* __restrict__ w_dT,
                            short* __restrict__ w_fT) {
    const int T1 = OUT * EMB;
    const int T2 = NDL * OUT * OUT;
    const int T3 = 16 * OUT;
    int total = T1 + T2 + T3;
    for (int i = blockIdx.x * blockDim.x + threadIdx.x; i < total; i += gridDim.x * blockDim.x) {
        if (i < T1) {
            int n = i >> 7, k = i & 127;
            w_upT[i] = f2bf(w_up[k * OUT + n]);
        } else if (i < T1 + T2) {
            int j = i - T1;
            int l = j >> 16, o = (j >> 8) & 255, k = j & 255;
            w_dT[j] = f2bf(w_dense[(l << 16) + (k << 8) + o]);
        } else {
            int j = i - T1 - T2;
            int t = j >> 8, k = j & 255;
            w_fT[j] = (t < NTGT) ? f2bf(w_final[k * NTGT + t]) : (short)0;
        }
    }
}

// ---------------- edge stream + atomic scatter ----------------
// No CSR. Edges processed in natural order: m is read perfectly sequentially
// (one wave per edge row, float2/lane = 512B coalesced; 4 consecutive edges
// per wave-iter = 2KB contiguous). The random access moves to t0 (12.8 MB
// fp32, Infinity-Cache-resident) via fire-and-forget global_atomic_add_f32
// on consecutive addresses.

__global__ __launch_bounds__(256) void edge_kernel(
    const float* __restrict__ m, const float* __restrict__ rbf,
    const float* __restrict__ w_rbf, const int* __restrict__ edge_src,
    float* __restrict__ t0, int E) {

    const int lane = threadIdx.x & 63;
    const int wave = threadIdx.x >> 6;

    float2 wq[RAD];
#pragma unroll
    for (int r = 0; r < RAD; r++) wq[r] = *(const float2*)&w_rbf[r * EMB + 2 * lane];

    const int base = (blockIdx.x * 4 + wave) * 4;
    if (base >= E) return;

    if (base + 4 <= E) {
        int sv[4];
        float2 mv[4];
        float2 r0[4], r1[4], r2[4];
#pragma unroll
        for (int j = 0; j < 4; j++) sv[j] = edge_src[base + j];
#pragma unroll
        for (int j = 0; j < 4; j++) {
            const float* rb = &rbf[(size_t)(base + j) * RAD];
            r0[j] = *(const float2*)&rb[0];
            r1[j] = *(const float2*)&rb[2];
            r2[j] = *(const float2*)&rb[4];
            mv[j] = *(const float2*)&m[(size_t)(base + j) * EMB + 2 * lane];
        }
#pragma unroll
        for (int j = 0; j < 4; j++) {
            float cx = wq[0].x * r0[j].x + wq[1].x * r0[j].y
                     + wq[2].x * r1[j].x + wq[3].x * r1[j].y
                     + wq[4].x * r2[j].x + wq[5].x * r2[j].y;
            float cy = wq[0].y * r0[j].x + wq[1].y * r0[j].y
                     + wq[2].y * r1[j].x + wq[3].y * r1[j].y
                     + wq[4].y * r2[j].x + wq[5].y * r2[j].y;
            float* dst = &t0[(size_t)sv[j] * EMB + 2 * lane];
            atomicAdd(&dst[0], mv[j].x * cx);
            atomicAdd(&dst[1], mv[j].y * cy);
        }
    } else {
        for (int i = base; i < E; i++) {
            int s0 = edge_src[i];
            const float* rb = &rbf[(size_t)i * RAD];
            float2 p0 = *(const float2*)&rb[0];
            float2 p1 = *(const float2*)&rb[2];
            float2 p2 = *(const float2*)&rb[4];
            float2 m0 = *(const float2*)&m[(size_t)i * EMB + 2 * lane];
            float cx = wq[0].x * p0.x + wq[1].x * p0.y + wq[2].x * p1.x
                     + wq[3].x * p1.y + wq[4].x * p2.x + wq[5].x * p2.y;
            float cy = wq[0].y * p0.x + wq[1].y * p0.y + wq[2].y * p1.x
                     + wq[3].y * p1.y + wq[4].y * p2.x + wq[5].y * p2.y;
            float* dst = &t0[(size_t)s0 * EMB + 2 * lane];
            atomicAdd(&dst[0], m0.x * cx);
            atomicAdd(&dst[1], m0.y * cy);
        }
    }
}

// ---------------- node MLP chain via MFMA + per-graph reduce ----------------

__global__ __launch_bounds__(256) void chain_kernel(
    const float* __restrict__ t0,
    const short* __restrict__ w_upT, const short* __restrict__ w_dT,
    const float* __restrict__ b_dense, const short* __restrict__ w_fT,
    const int* __restrict__ node2graph, float* __restrict__ out, int N) {

    __shared__ short sA[2][MT * S];

    int tid = threadIdx.x;
    int n0 = blockIdx.x * MT;
    int wave = tid >> 6, lane = tid & 63;
    int lo = lane & 15;
    int quad = lane >> 4;
    int kq = quad * 8;
    int wcol = wave * 64;

    {
        int r = tid >> 3;              // 32 rows
        int c = (tid & 7) * 16;        // 16 fp32 cols per thread
        float4 v0 = {0, 0, 0, 0}, v1 = v0, v2 = v0, v3 = v0;
        if (n0 + r < N) {
            const float4* src = (const float4*)(t0 + (size_t)(n0 + r) * EMB + c);
            v0 = src[0]; v1 = src[1]; v2 = src[2]; v3 = src[3];
        }
        uint4 pk0, pk1;
        pk0.x = pack2bf(v0.x, v0.y); pk0.y = pack2bf(v0.z, v0.w);
        pk0.z = pack2bf(v1.x, v1.y); pk0.w = pack2bf(v1.z, v1.w);
        pk1.x = pack2bf(v2.x, v2.y); pk1.y = pack2bf(v2.z, v2.w);
        pk1.z = pack2bf(v3.x, v3.y); pk1.w = pack2bf(v3.z, v3.w);
        *(uint4*)&sA[0][r * S + c] = pk0;
        *(uint4*)&sA[0][r * S + c + 8] = pk1;
    }
    __syncthreads();

    auto layer = [&](int cur, int K, const short* __restrict__ Bt,
                     const float* __restrict__ bias, bool act) {
        floatx4 acc[2][4];
#pragma unroll
        for (int mt = 0; mt < 2; mt++)
#pragma unroll
            for (int nt = 0; nt < 4; nt++)
                acc[mt][nt] = floatx4{0.f, 0.f, 0.f, 0.f};

        for (int kc = 0; kc < K; kc += 32) {
            short8 a0 = *(const short8*)&sA[cur][(lo) * S + kc + kq];
            short8 a1 = *(const short8*)&sA[cur][(16 + lo) * S + kc + kq];
#pragma unroll
            for (int nt = 0; nt < 4; nt++) {
                int n = wcol + nt * 16 + lo;
                short8 b = *(const short8*)&Bt[(size_t)n * K + kc + kq];
                acc[0][nt] = __builtin_amdgcn_mfma_f32_16x16x32_bf16(a0, b, acc[0][nt], 0, 0, 0);
                acc[1][nt] = __builtin_amdgcn_mfma_f32_16x16x32_bf16(a1, b, acc[1][nt], 0, 0, 0);
            }
        }

        float bv[4];
#pragma unroll
        for (int nt = 0; nt < 4; nt++) bv[nt] = bias ? bias[wcol + nt * 16 + lo] : 0.f;

        short* dst = sA[cur ^ 1];
#pragma unroll
        for (int mt = 0; mt < 2; mt++)
#pragma unroll
            for (int nt = 0; nt < 4; nt++) {
                int n = wcol + nt * 16 + lo;
#pragma unroll
                for (int i = 0; i < 4; i++) {
                    int mrow = mt * 16 + quad * 4 + i;
                    float x = acc[mt][nt][i] + bv[nt];
                    if (act) x = x / (1.f + __expf(-x));
                    dst[mrow * S + n] = f2bf(x);
                }
            }
        __syncthreads();
    };

    layer(0, EMB, w_upT, nullptr, false);
    layer(1, OUT, w_dT + 0 * OUT * OUT, b_dense + 0 * OUT, true);
    layer(0, OUT, w_dT + 1 * OUT * OUT, b_dense + 1 * OUT, true);
    layer(1, OUT, w_dT + 2 * OUT * OUT, b_dense + 2 * OUT, true);

    if (wave == 0) {
        floatx4 facc[2];
        facc[0] = floatx4{0.f, 0.f, 0.f, 0.f};
        facc[1] = floatx4{0.f, 0.f, 0.f, 0.f};
        for (int kc = 0; kc < OUT; kc += 32) {
            short8 a0 = *(const short8*)&sA[0][(lo) * S + kc + kq];
            short8 a1 = *(const short8*)&sA[0][(16 + lo) * S + kc + kq];
            short8 b = *(const short8*)&w_fT[lo * OUT + kc + kq];
            facc[0] = __builtin_amdgcn_mfma_f32_16x16x32_bf16(a0, b, facc[0], 0, 0, 0);
            facc[1] = __builtin_amdgcn_mfma_f32_16x16x32_bf16(a1, b, facc[1], 0, 0, 0);
        }
        if (lo < NTGT) {
#pragma unroll
            for (int mt = 0; mt < 2; mt++)
#pragma unroll
                for (int i = 0; i < 4; i++) {
                    int node = n0 + mt * 16 + quad * 4 + i;
                    if (node < N)
                        atomicAdd(&out[node2graph[node] * NTGT + lo], facc[mt][i]);
                }
        }
    }
}

// ---------------- launch ----------------

extern "C" void kernel_launch(void* const* d_in, const int* in_sizes, int n_in,
                              void* d_out, int out_size, void* d_ws, size_t ws_size,
                              hipStream_t stream) {
    const float* m        = (const float*)d_in[0];
    const float* rbf      = (const float*)d_in[1];
    const int*   edge_src = (const int*)d_in[2];
    const int*   node2g   = (const int*)d_in[3];
    const float* w_rbf    = (const float*)d_in[4];
    const float* w_up     = (const float*)d_in[5];
    const float* w_dense  = (const float*)d_in[6];
    const float* b_dense  = (const float*)d_in[7];
    const float* w_final  = (const float*)d_in[8];

    int E = in_sizes[2];
    int N = in_sizes[3];
    float* out = (float*)d_out;

    char* p = (char*)d_ws;
    auto alloc = [&](size_t bytes) {
        char* r = p;
        p += (bytes + 255) & ~(size_t)255;
        return r;
    };
    float* t0     = (float*)alloc((size_t)N * EMB * 4);
    short* w_upT  = (short*)alloc((size_t)OUT * EMB * 2);
    short* w_dT   = (short*)alloc((size_t)NDL * OUT * OUT * 2);
    short* w_fT   = (short*)alloc((size_t)16 * OUT * 2);

    hipMemsetAsync(t0, 0, (size_t)N * EMB * 4, stream);
    hipMemsetAsync(d_out, 0, (size_t)out_size * 4, stream);

    prep_kernel<<<512, 256, 0, stream>>>(w_up, w_dense, w_final, w_upT, w_dT, w_fT);
    edge_kernel<<<(E + 15) / 16, 256, 0, stream>>>(m, rbf, w_rbf, edge_src, t0, E);
    chain_kernel<<<(N + MT - 1) / MT, 256, 0, stream>>>(t0, w_upT, w_dT, b_dense,
                                                        w_fT, node2g, out, N);
}